// Round 1
// baseline (3853.270 us; speedup 1.0000x reference)
//
#include <hip/hip_runtime.h>
#include <math.h>

#define NS   3072
#define KT   64
#define CC   128
#define TDIM 100
#define TGN  98304
#define TH   32
#define CH   512
#define ZS   129   // LDS row stride (129 % 32 == 1 -> conflict-free rows AND columns)

__device__ __forceinline__ float gelu_f(float x) {
    float x3 = x * x * x;
    float u  = 0.7978845608028654f * (x + 0.044715f * x3);
    return 0.5f * x * (1.0f + tanhf(u));
}

// One workgroup per seed n. z[64][128] resident in LDS through projection,
// 2 mixer layers, and masked mean. 256 threads = 4 waves.
__global__ __launch_bounds__(256, 2)
void gm_mixer(const float* __restrict__ edge_feat,
              const float* __restrict__ seed_times,
              const float* __restrict__ nbr_time,
              const float* __restrict__ time_w,
              const float* __restrict__ proj_W,
              const float* __restrict__ proj_b,
              const float* __restrict__ ln1_g, const float* __restrict__ ln1_b,
              const float* __restrict__ tW1,   const float* __restrict__ tb1,
              const float* __restrict__ tW2,   const float* __restrict__ tb2,
              const float* __restrict__ ln2_g, const float* __restrict__ ln2_b,
              const float* __restrict__ cW1,   const float* __restrict__ cb1,
              const float* __restrict__ cW2,   const float* __restrict__ cb2,
              const int*   __restrict__ nbr_nids,
              float* __restrict__ zmean)
{
    __shared__ float zbuf[KT * ZS];          // 33,024 B : residual stream z
    __shared__ float ubuf[KT * ZS];          // 33,024 B : tfeat / token-hidden / G-chunk
    __shared__ float mArr[KT], rArr[KT], maskArr[KT];

    const int n    = blockIdx.x;
    const int t    = threadIdx.x;
    const int lane = t & 63;
    const int w    = t >> 6;

    // ---------------- time features: ubuf[k*TDIM + tt] = cos(dt_k * w_tt)
    const float st = seed_times[n];
    for (int idx = t; idx < KT * TDIM; idx += 256) {
        int k  = idx / TDIM;
        int tt = idx - k * TDIM;
        float dt = st - nbr_time[n * KT + k];
        ubuf[idx] = cosf(dt * time_w[tt]);
    }
    if (t < KT) maskArr[t] = (nbr_nids[n * KT + t] != 0) ? 1.0f : 0.0f;
    __syncthreads();

    // ---------------- projection: z[k][c] = [ef | tfeat] @ proj_W + proj_b
    {
        const int c0 = lane, c1 = lane + 64;
        const int kb = w * 16;
        const float* ef = edge_feat + (size_t)n * KT * CC;
        float acc0[16], acc1[16];
        const float pb0 = proj_b[c0], pb1 = proj_b[c1];
        #pragma unroll
        for (int i = 0; i < 16; ++i) { acc0[i] = pb0; acc1[i] = pb1; }
        for (int j = 0; j < CC; ++j) {
            float w0 = proj_W[j * CC + c0];
            float w1 = proj_W[j * CC + c1];
            #pragma unroll
            for (int i = 0; i < 16; ++i) {
                float x = ef[(kb + i) * CC + j];     // wave-uniform broadcast load
                acc0[i] += x * w0; acc1[i] += x * w1;
            }
        }
        for (int j = 0; j < TDIM; ++j) {
            float w0 = proj_W[(CC + j) * CC + c0];
            float w1 = proj_W[(CC + j) * CC + c1];
            #pragma unroll
            for (int i = 0; i < 16; ++i) {
                float x = ubuf[(kb + i) * TDIM + j]; // LDS broadcast
                acc0[i] += x * w0; acc1[i] += x * w1;
            }
        }
        #pragma unroll
        for (int i = 0; i < 16; ++i) {
            zbuf[(kb + i) * ZS + c0] = acc0[i];
            zbuf[(kb + i) * ZS + c1] = acc1[i];
        }
    }
    __syncthreads();

    // ---------------- mixer layers
    for (int l = 0; l < 2; ++l) {
        // LN1 stats (wave 0: one lane per row)
        if (t < KT) {
            float s = 0.f, s2 = 0.f;
            for (int c = 0; c < CC; ++c) { float v = zbuf[t * ZS + c]; s += v; s2 += v * v; }
            float m = s * (1.0f / CC);
            float var = s2 * (1.0f / CC) - m * m;
            mArr[t] = m; rArr[t] = rsqrtf(var + 1e-5f);
        }
        __syncthreads();

        // token mix 1: hid[hh][c] = gelu( sum_k LN(z)[k][c] * tW1[k][hh] + tb1[hh] )
        {
            const int c  = t & 127;
            const int hg = t >> 7;      // 0..1 -> 16 hh each
            const float g1c = ln1_g[l * CC + c], b1c = ln1_b[l * CC + c];
            float acc[16];
            #pragma unroll
            for (int hh = 0; hh < 16; ++hh) acc[hh] = 0.f;
            const float* tw = tW1 + l * KT * TH + hg * 16;
            for (int k = 0; k < KT; ++k) {
                float zn = (zbuf[k * ZS + c] - mArr[k]) * rArr[k] * g1c + b1c;
                #pragma unroll
                for (int hh = 0; hh < 16; ++hh) acc[hh] += zn * tw[k * TH + hh];
            }
            #pragma unroll
            for (int hh = 0; hh < 16; ++hh) {
                float v = acc[hh] + tb1[l * TH + hg * 16 + hh];
                ubuf[(hg * 16 + hh) * ZS + c] = gelu_f(v);
            }
        }
        __syncthreads();

        // token mix 2: z[k][c] += sum_hh hid[hh][c] * tW2[hh][k] + tb2[k]
        {
            const int c  = t & 127;
            const int kg = t >> 7;
            for (int k = kg * 32; k < kg * 32 + 32; ++k) {
                float acc = tb2[l * KT + k];
                const float* tw2 = tW2 + l * TH * KT + k;
                #pragma unroll
                for (int hh = 0; hh < TH; ++hh) acc += ubuf[hh * ZS + c] * tw2[hh * KT];
                zbuf[k * ZS + c] += acc;
            }
        }
        __syncthreads();

        // LN2 stats
        if (t < KT) {
            float s = 0.f, s2 = 0.f;
            for (int c = 0; c < CC; ++c) { float v = zbuf[t * ZS + c]; s += v; s2 += v * v; }
            float m = s * (1.0f / CC);
            float var = s2 * (1.0f / CC) - m * m;
            mArr[t] = m; rArr[t] = rsqrtf(var + 1e-5f);
        }
        __syncthreads();

        // channel mix: z += gelu(LN(z) @ cW1 + cb1) @ cW2 + cb2
        // thread owns rows {rg, rg+32} x 16 cols; hidden (512) processed in 4 chunks of 128
        {
            const int rg = t & 31;
            const int g8 = t >> 5;      // 0..7
            const float m0 = mArr[rg],      r0 = rArr[rg];
            const float m1 = mArr[rg + 32], r1 = rArr[rg + 32];
            float accB[2][16];
            #pragma unroll
            for (int x = 0; x < 16; ++x) { accB[0][x] = 0.f; accB[1][x] = 0.f; }

            for (int jc = 0; jc < 4; ++jc) {
                // phase A: G = LN(z) @ cW1[:, chunk]
                float accA[2][16];
                #pragma unroll
                for (int x = 0; x < 16; ++x) { accA[0][x] = 0.f; accA[1][x] = 0.f; }
                const int j0 = g8 * 16;
                const float* w1p = cW1 + l * CC * CH + jc * 128 + j0;
                for (int c = 0; c < CC; ++c) {
                    float g2c = ln2_g[l * CC + c], b2c = ln2_b[l * CC + c];
                    float a0 = r0 * g2c, a1 = r1 * g2c;
                    float h0 = zbuf[rg * ZS + c]        * a0 + (b2c - m0 * a0);
                    float h1 = zbuf[(rg + 32) * ZS + c] * a1 + (b2c - m1 * a1);
                    const float* wr = w1p + c * CH;
                    #pragma unroll
                    for (int jj = 0; jj < 16; ++jj) {
                        float wv = wr[jj];
                        accA[0][jj] += h0 * wv;
                        accA[1][jj] += h1 * wv;
                    }
                }
                {
                    const float* cb1p = cb1 + l * CH + jc * 128 + j0;
                    #pragma unroll
                    for (int jj = 0; jj < 16; ++jj) {
                        ubuf[rg * ZS + j0 + jj]        = gelu_f(accA[0][jj] + cb1p[jj]);
                        ubuf[(rg + 32) * ZS + j0 + jj] = gelu_f(accA[1][jj] + cb1p[jj]);
                    }
                }
                __syncthreads();   // G chunk visible
                // phase B: accB += G @ cW2[chunk, :]
                const float* w2p = cW2 + l * CH * CC + (jc * 128) * CC + g8 * 16;
                for (int j = 0; j < 128; ++j) {
                    float gv0 = ubuf[rg * ZS + j];
                    float gv1 = ubuf[(rg + 32) * ZS + j];
                    const float* wr = w2p + j * CC;
                    #pragma unroll
                    for (int cc = 0; cc < 16; ++cc) {
                        float wv = wr[cc];
                        accB[0][cc] += gv0 * wv;
                        accB[1][cc] += gv1 * wv;
                    }
                }
                __syncthreads();   // done reading G before next chunk overwrites
            }
            // residual add
            const float* cb2p = cb2 + l * CC + g8 * 16;
            #pragma unroll
            for (int cc = 0; cc < 16; ++cc) {
                zbuf[rg * ZS + g8 * 16 + cc]        += accB[0][cc] + cb2p[cc];
                zbuf[(rg + 32) * ZS + g8 * 16 + cc] += accB[1][cc] + cb2p[cc];
            }
        }
        __syncthreads();
    }

    // ---------------- masked mean over K -> zmean[n][c]
    if (t < CC) {
        float acc = 0.f, ms = 0.f;
        for (int k = 0; k < KT; ++k) {
            float mk = maskArr[k];
            ms  += mk;
            acc += zbuf[k * ZS + t] * mk;
        }
        zmean[n * CC + t] = acc / fmaxf(ms, 1.0f);
    }
}

// Per-seed: ragged segment mean over tg (sorted tg_seg, binary search),
// + node_feat[seed], then out = [zmean | z_node] @ out_W + out_b
__global__ __launch_bounds__(128)
void gm_out(const float* __restrict__ zmean,
            const float* __restrict__ node_feat,
            const float* __restrict__ out_W,
            const float* __restrict__ out_b,
            const int*   __restrict__ tg_idx,
            const int*   __restrict__ tg_seg,
            const int*   __restrict__ seed_ids,
            float* __restrict__ outp)
{
    __shared__ float zmL[CC], znL[CC];
    const int n = blockIdx.x;
    const int c = threadIdx.x;

    // lower_bound(n) and lower_bound(n+1) over sorted tg_seg (uniform branches)
    int a = 0, b = TGN;
    while (a < b) { int mm = (a + b) >> 1; if (tg_seg[mm] < n) a = mm + 1; else b = mm; }
    const int lo = a;
    int a2 = lo, b2 = TGN;
    while (a2 < b2) { int mm = (a2 + b2) >> 1; if (tg_seg[mm] < n + 1) a2 = mm + 1; else b2 = mm; }
    const int hi = a2;

    float acc = 0.f;
    for (int i = lo; i < hi; ++i) {
        int nid = tg_idx[i];
        acc += node_feat[(size_t)nid * CC + c];
    }
    float cnt = (float)(hi - lo);
    float tg  = acc / fmaxf(cnt, 1.0f);
    float zn  = tg + node_feat[(size_t)seed_ids[n] * CC + c];

    zmL[c] = zmean[n * CC + c];
    znL[c] = zn;
    __syncthreads();

    float o = out_b[c];
    for (int j = 0; j < CC; ++j) o += zmL[j] * out_W[j * 128 + c];
    for (int j = 0; j < CC; ++j) o += znL[j] * out_W[(CC + j) * 128 + c];
    outp[n * 128 + c] = o;
}

extern "C" void kernel_launch(void* const* d_in, const int* in_sizes, int n_in,
                              void* d_out, int out_size, void* d_ws, size_t ws_size,
                              hipStream_t stream)
{
    const float* edge_feat  = (const float*)d_in[0];
    const float* seed_times = (const float*)d_in[1];
    const float* nbr_time   = (const float*)d_in[2];
    const float* node_feat  = (const float*)d_in[3];
    const float* time_w     = (const float*)d_in[4];
    const float* proj_W     = (const float*)d_in[5];
    const float* proj_b     = (const float*)d_in[6];
    const float* ln1_g      = (const float*)d_in[7];
    const float* ln1_b      = (const float*)d_in[8];
    const float* tW1        = (const float*)d_in[9];
    const float* tb1        = (const float*)d_in[10];
    const float* tW2        = (const float*)d_in[11];
    const float* tb2        = (const float*)d_in[12];
    const float* ln2_g      = (const float*)d_in[13];
    const float* ln2_b      = (const float*)d_in[14];
    const float* cW1        = (const float*)d_in[15];
    const float* cb1        = (const float*)d_in[16];
    const float* cW2        = (const float*)d_in[17];
    const float* cb2        = (const float*)d_in[18];
    const float* out_W      = (const float*)d_in[19];
    const float* out_b      = (const float*)d_in[20];
    const int*   nbr_nids   = (const int*)d_in[21];
    const int*   tg_idx     = (const int*)d_in[22];
    const int*   tg_seg     = (const int*)d_in[23];
    const int*   seed_ids   = (const int*)d_in[24];

    float* zmean = (float*)d_ws;   // NS*CC floats = 1.57 MB scratch

    gm_mixer<<<NS, 256, 0, stream>>>(edge_feat, seed_times, nbr_time, time_w,
                                     proj_W, proj_b, ln1_g, ln1_b, tW1, tb1, tW2, tb2,
                                     ln2_g, ln2_b, cW1, cb1, cW2, cb2, nbr_nids, zmean);
    gm_out<<<NS, 128, 0, stream>>>(zmean, node_feat, out_W, out_b,
                                   tg_idx, tg_seg, seed_ids, (float*)d_out);
}

// Round 2
// 673.834 us; speedup vs baseline: 5.7184x; 5.7184x over previous
//
#include <hip/hip_runtime.h>
#include <math.h>

#define NS   3072
#define KT   64
#define CC   128
#define TDIM 100
#define TGN  98304
#define TH   32
#define CH   512
#define ZS   132   // zbuf fp32 stride (132%32=4; float4-aligned)
#define PS   136   // LNzb/Gb bf16 stride (272B row -> 2-way conflict on b128 reads = free)
#define PS2  264   // Ab (projection A) bf16 stride
#define PSK  72    // LNz1T stride
#define PSH  40    // G2T stride

typedef __attribute__((ext_vector_type(8))) short bf16x8;
typedef __attribute__((ext_vector_type(4))) float f32x4;

__device__ __forceinline__ unsigned short f2bf(float f) {
    unsigned int u = __float_as_uint(f);
    return (unsigned short)((u + 0x7FFFu + ((u >> 16) & 1u)) >> 16);   // RNE
}
__device__ __forceinline__ float gelu_f(float x) {
    float u = 0.7978845608028654f * (x + 0.044715f * x * x * x);
    return 0.5f * x * (1.0f + tanhf(u));
}

// ---- prepass: bf16-convert + transpose all weights into d_ws ------------
// projWTb[128][256] (K padded 228->256, zero), tW1Tb[2][32][64], tW2Tb[2][64][32],
// cW1Tb[2][512][128], cW2Tb[2][128][512]
__global__ void gm_prep(const float* __restrict__ proj_W, const float* __restrict__ tW1,
                        const float* __restrict__ tW2, const float* __restrict__ cW1,
                        const float* __restrict__ cW2,
                        unsigned short* __restrict__ projWTb, unsigned short* __restrict__ tW1Tb,
                        unsigned short* __restrict__ tW2Tb, unsigned short* __restrict__ cW1Tb,
                        unsigned short* __restrict__ cW2Tb)
{
    int e = blockIdx.x * 256 + threadIdx.x;
    if (e < 32768) {
        int c = e >> 8, j = e & 255;
        projWTb[e] = (j < 228) ? f2bf(proj_W[j * CC + c]) : (unsigned short)0;
    }
    int e1 = e - 32768;
    if (e1 >= 0 && e1 < 4096) {           // tW1T[l][h][k] = tW1[l][k][h]
        int l = e1 >> 11, rem = e1 & 2047, h = rem >> 6, k = rem & 63;
        tW1Tb[e1] = f2bf(tW1[(l * KT + k) * TH + h]);
    }
    int e2 = e - 36864;
    if (e2 >= 0 && e2 < 4096) {           // tW2T[l][k][h] = tW2[l][h][k]
        int l = e2 >> 11, rem = e2 & 2047, k = rem >> 5, h = rem & 31;
        tW2Tb[e2] = f2bf(tW2[(l * TH + h) * KT + k]);
    }
    int e3 = e - 40960;
    if (e3 >= 0 && e3 < 131072) {         // cW1T[l][h][c] = cW1[l][c][h]
        int l = e3 >> 16, rem = e3 & 65535, h = rem >> 7, c = rem & 127;
        cW1Tb[e3] = f2bf(cW1[(l * CC + c) * CH + h]);
    }
    int e4 = e - 172032;
    if (e4 >= 0 && e4 < 131072) {         // cW2T[l][c][h] = cW2[l][h][c]
        int l = e4 >> 16, rem = e4 & 65535, c = rem >> 9, h = rem & 511;
        cW2Tb[e4] = f2bf(cW2[(l * CH + h) * CC + c]);
    }
}

// ---- main mixer: one WG (4 waves) per seed; z fp32 in LDS; MFMA everywhere
__global__ __launch_bounds__(256, 2)
void gm_mixer(const float* __restrict__ edge_feat,
              const float* __restrict__ seed_times,
              const float* __restrict__ nbr_time,
              const float* __restrict__ time_w,
              const float* __restrict__ proj_b,
              const float* __restrict__ ln1_g, const float* __restrict__ ln1_b,
              const float* __restrict__ tb1,   const float* __restrict__ tb2,
              const float* __restrict__ ln2_g, const float* __restrict__ ln2_b,
              const float* __restrict__ cb1,   const float* __restrict__ cb2,
              const int*   __restrict__ nbr_nids,
              const unsigned short* __restrict__ projWTb,
              const unsigned short* __restrict__ tW1Tb,
              const unsigned short* __restrict__ tW2Tb,
              const unsigned short* __restrict__ cW1Tb,
              const unsigned short* __restrict__ cW2Tb,
              float* __restrict__ zmean)
{
    __shared__ float zbuf[KT * ZS];          // 33,792 B residual stream (fp32)
    __shared__ short ubuf[17408];            // 34,816 B phase-union buffer
    __shared__ float mArr[KT], rArr[KT], maskArr[KT];

    const int n  = blockIdx.x;
    const int t  = threadIdx.x;
    const int w  = t >> 6;        // wave 0..3
    const int l  = t & 63;
    const int lr = l & 15;        // row-in-tile / col-in-tile
    const int kg = l >> 4;        // k-group 0..3

    const f32x4 zero4 = {0.f, 0.f, 0.f, 0.f};

    // ---------- stage dt (into mArr) + mask; edge_feat -> Ab bf16
    short* Ab = ubuf;                         // [64][PS2]
    if (t < KT) {
        mArr[t]    = seed_times[n] - nbr_time[n * KT + t];
        maskArr[t] = (nbr_nids[n * KT + t] != 0) ? 1.0f : 0.0f;
    }
    {
        const float4* ef4 = (const float4*)(edge_feat + (size_t)n * KT * CC);
        #pragma unroll
        for (int it = 0; it < 8; ++it) {
            int i4 = it * 256 + t;
            int k  = i4 >> 5;
            int c  = (i4 & 31) << 2;
            float4 v = ef4[i4];
            ushort4 o;
            o.x = f2bf(v.x); o.y = f2bf(v.y); o.z = f2bf(v.z); o.w = f2bf(v.w);
            *(ushort4*)&Ab[k * PS2 + c] = o;
        }
    }
    __syncthreads();
    // time features (cols 128..227), zero-pad 228..255
    for (int idx = t; idx < KT * 128; idx += 256) {
        int k = idx >> 7, j = idx & 127;
        float val = 0.0f;
        if (j < TDIM) val = cosf(mArr[k] * time_w[j]);
        Ab[k * PS2 + 128 + j] = (short)f2bf(val);
    }
    __syncthreads();

    // ---------- projection MFMA: M=64, N=128, K=256 (wave owns 2 n-tiles)
    {
        f32x4 acc[4][2];
        #pragma unroll
        for (int mt = 0; mt < 4; ++mt) { acc[mt][0] = zero4; acc[mt][1] = zero4; }
        for (int ks = 0; ks < 8; ++ks) {
            bf16x8 b0 = *(const bf16x8*)&projWTb[(w * 32 + lr)      * 256 + ks * 32 + kg * 8];
            bf16x8 b1 = *(const bf16x8*)&projWTb[(w * 32 + 16 + lr) * 256 + ks * 32 + kg * 8];
            #pragma unroll
            for (int mt = 0; mt < 4; ++mt) {
                bf16x8 a = *(const bf16x8*)&Ab[(mt * 16 + lr) * PS2 + ks * 32 + kg * 8];
                acc[mt][0] = __builtin_amdgcn_mfma_f32_16x16x32_bf16(a, b0, acc[mt][0], 0, 0, 0);
                acc[mt][1] = __builtin_amdgcn_mfma_f32_16x16x32_bf16(a, b1, acc[mt][1], 0, 0, 0);
            }
        }
        __syncthreads();   // done with Ab before union reuse
        #pragma unroll
        for (int mt = 0; mt < 4; ++mt)
            #pragma unroll
            for (int nt = 0; nt < 2; ++nt) {
                int col = w * 32 + nt * 16 + lr;
                float pb = proj_b[col];
                #pragma unroll
                for (int r = 0; r < 4; ++r)
                    zbuf[(mt * 16 + kg * 4 + r) * ZS + col] = acc[mt][nt][r] + pb;
            }
    }
    __syncthreads();

    short* LNz1T = ubuf;               // [128][PSK] LN1(z) transposed bf16
    short* G2T   = ubuf + 128 * PSK;   // [128][PSH] token hidden transposed bf16
    short* LNzb  = ubuf;               // [64][PS]   LN2(z) bf16
    short* Gb    = ubuf + 64 * PS;     // [64][PS]   gelu chunk bf16

    for (int lay = 0; lay < 2; ++lay) {
        // ---------- LN1 stats (256 threads, 4/row, shfl combine)
        {
            int rr = t >> 2, part = t & 3;
            const float4* zp = (const float4*)&zbuf[rr * ZS + part * 32];
            float s = 0.f, s2 = 0.f;
            #pragma unroll
            for (int i = 0; i < 8; ++i) {
                float4 v = zp[i];
                s  += v.x + v.y + v.z + v.w;
                s2 += v.x * v.x + v.y * v.y + v.z * v.z + v.w * v.w;
            }
            s += __shfl_xor(s, 1); s2 += __shfl_xor(s2, 1);
            s += __shfl_xor(s, 2); s2 += __shfl_xor(s2, 2);
            if (part == 0) {
                float m = s * (1.0f / CC);
                float var = s2 * (1.0f / CC) - m * m;
                mArr[rr] = m; rArr[rr] = rsqrtf(var + 1e-5f);
            }
        }
        __syncthreads();

        // ---------- LNz1T materialize: LNz1T[c][k]
        {
            const float* g1 = ln1_g + lay * CC;
            const float* b1 = ln1_b + lay * CC;
            for (int idx = t; idx < 4096; idx += 256) {
                int c = idx >> 5, k2 = (idx & 31) << 1;
                float gc = g1[c], bc = b1[c];
                float v0 = (zbuf[k2 * ZS + c]       - mArr[k2])     * rArr[k2]     * gc + bc;
                float v1 = (zbuf[(k2 + 1) * ZS + c] - mArr[k2 + 1]) * rArr[k2 + 1] * gc + bc;
                unsigned int pack = (unsigned int)f2bf(v0) | ((unsigned int)f2bf(v1) << 16);
                *(unsigned int*)&LNz1T[c * PSK + k2] = pack;
            }
        }
        __syncthreads();

        // ---------- token mix 1 MFMA: M=32(hh), N=128(c), K=64
        {
            f32x4 acc1[2][2];
            #pragma unroll
            for (int mt = 0; mt < 2; ++mt) { acc1[mt][0] = zero4; acc1[mt][1] = zero4; }
            #pragma unroll
            for (int ks = 0; ks < 2; ++ks) {
                bf16x8 bb0 = *(const bf16x8*)&LNz1T[(w * 32 + lr)      * PSK + ks * 32 + kg * 8];
                bf16x8 bb1 = *(const bf16x8*)&LNz1T[(w * 32 + 16 + lr) * PSK + ks * 32 + kg * 8];
                #pragma unroll
                for (int mt = 0; mt < 2; ++mt) {
                    bf16x8 a = *(const bf16x8*)&tW1Tb[lay * 2048 + (mt * 16 + lr) * 64 + ks * 32 + kg * 8];
                    acc1[mt][0] = __builtin_amdgcn_mfma_f32_16x16x32_bf16(a, bb0, acc1[mt][0], 0, 0, 0);
                    acc1[mt][1] = __builtin_amdgcn_mfma_f32_16x16x32_bf16(a, bb1, acc1[mt][1], 0, 0, 0);
                }
            }
            #pragma unroll
            for (int mt = 0; mt < 2; ++mt)
                #pragma unroll
                for (int nt = 0; nt < 2; ++nt) {
                    int col = w * 32 + nt * 16 + lr;
                    #pragma unroll
                    for (int r = 0; r < 4; ++r) {
                        int row = mt * 16 + kg * 4 + r;
                        float v = acc1[mt][nt][r] + tb1[lay * TH + row];
                        G2T[col * PSH + row] = (short)f2bf(gelu_f(v));   // wave-local cols
                    }
                }
        }
        // no barrier: wave w wrote exactly the G2T cols it reads below
        // ---------- token mix 2 MFMA: M=64(k), N=128(c), K=32 + residual
        {
            f32x4 acc2[4][2];
            #pragma unroll
            for (int mt = 0; mt < 4; ++mt) { acc2[mt][0] = zero4; acc2[mt][1] = zero4; }
            bf16x8 bb0 = *(const bf16x8*)&G2T[(w * 32 + lr)      * PSH + kg * 8];
            bf16x8 bb1 = *(const bf16x8*)&G2T[(w * 32 + 16 + lr) * PSH + kg * 8];
            #pragma unroll
            for (int mt = 0; mt < 4; ++mt) {
                bf16x8 a = *(const bf16x8*)&tW2Tb[lay * 2048 + (mt * 16 + lr) * 32 + kg * 8];
                acc2[mt][0] = __builtin_amdgcn_mfma_f32_16x16x32_bf16(a, bb0, acc2[mt][0], 0, 0, 0);
                acc2[mt][1] = __builtin_amdgcn_mfma_f32_16x16x32_bf16(a, bb1, acc2[mt][1], 0, 0, 0);
            }
            #pragma unroll
            for (int mt = 0; mt < 4; ++mt)
                #pragma unroll
                for (int nt = 0; nt < 2; ++nt) {
                    int col = w * 32 + nt * 16 + lr;
                    #pragma unroll
                    for (int r = 0; r < 4; ++r) {
                        int row = mt * 16 + kg * 4 + r;
                        zbuf[row * ZS + col] += acc2[mt][nt][r] + tb2[lay * KT + row];
                    }
                }
        }
        __syncthreads();

        // ---------- LN2 stats
        {
            int rr = t >> 2, part = t & 3;
            const float4* zp = (const float4*)&zbuf[rr * ZS + part * 32];
            float s = 0.f, s2 = 0.f;
            #pragma unroll
            for (int i = 0; i < 8; ++i) {
                float4 v = zp[i];
                s  += v.x + v.y + v.z + v.w;
                s2 += v.x * v.x + v.y * v.y + v.z * v.z + v.w * v.w;
            }
            s += __shfl_xor(s, 1); s2 += __shfl_xor(s2, 1);
            s += __shfl_xor(s, 2); s2 += __shfl_xor(s2, 2);
            if (part == 0) {
                float m = s * (1.0f / CC);
                float var = s2 * (1.0f / CC) - m * m;
                mArr[rr] = m; rArr[rr] = rsqrtf(var + 1e-5f);
            }
        }
        __syncthreads();

        // ---------- LNzb materialize: LNzb[k][c]
        {
            const float* g2 = ln2_g + lay * CC;
            const float* b2 = ln2_b + lay * CC;
            for (int idx = t; idx < 4096; idx += 256) {
                int k = idx >> 6, c2 = (idx & 63) << 1;
                float m = mArr[k], r = rArr[k];
                float v0 = (zbuf[k * ZS + c2]     - m) * r * g2[c2]     + b2[c2];
                float v1 = (zbuf[k * ZS + c2 + 1] - m) * r * g2[c2 + 1] + b2[c2 + 1];
                unsigned int pack = (unsigned int)f2bf(v0) | ((unsigned int)f2bf(v1) << 16);
                *(unsigned int*)&LNzb[k * PS + c2] = pack;
            }
        }
        __syncthreads();

        // ---------- channel mix: 4 hidden chunks of 128
        {
            f32x4 accB[4][2];
            #pragma unroll
            for (int mt = 0; mt < 4; ++mt) { accB[mt][0] = zero4; accB[mt][1] = zero4; }

            for (int jc = 0; jc < 4; ++jc) {
                f32x4 accA[4][2];
                #pragma unroll
                for (int mt = 0; mt < 4; ++mt) { accA[mt][0] = zero4; accA[mt][1] = zero4; }
                #pragma unroll
                for (int ks = 0; ks < 4; ++ks) {
                    const unsigned short* w1p = cW1Tb + lay * CH * CC
                                              + (jc * 128 + w * 32 + lr) * CC + ks * 32 + kg * 8;
                    bf16x8 b0 = *(const bf16x8*)w1p;
                    bf16x8 b1 = *(const bf16x8*)(w1p + 16 * CC);
                    #pragma unroll
                    for (int mt = 0; mt < 4; ++mt) {
                        bf16x8 a = *(const bf16x8*)&LNzb[(mt * 16 + lr) * PS + ks * 32 + kg * 8];
                        accA[mt][0] = __builtin_amdgcn_mfma_f32_16x16x32_bf16(a, b0, accA[mt][0], 0, 0, 0);
                        accA[mt][1] = __builtin_amdgcn_mfma_f32_16x16x32_bf16(a, b1, accA[mt][1], 0, 0, 0);
                    }
                }
                #pragma unroll
                for (int mt = 0; mt < 4; ++mt)
                    #pragma unroll
                    for (int nt = 0; nt < 2; ++nt) {
                        int col = w * 32 + nt * 16 + lr;
                        float cb = cb1[lay * CH + jc * 128 + col];
                        #pragma unroll
                        for (int r = 0; r < 4; ++r) {
                            int row = mt * 16 + kg * 4 + r;
                            Gb[row * PS + col] = (short)f2bf(gelu_f(accA[mt][nt][r] + cb));
                        }
                    }
                __syncthreads();
                #pragma unroll
                for (int ks = 0; ks < 4; ++ks) {
                    const unsigned short* w2p = cW2Tb + lay * CC * CH
                                              + (w * 32 + lr) * CH + jc * 128 + ks * 32 + kg * 8;
                    bf16x8 b0 = *(const bf16x8*)w2p;
                    bf16x8 b1 = *(const bf16x8*)(w2p + 16 * CH);
                    #pragma unroll
                    for (int mt = 0; mt < 4; ++mt) {
                        bf16x8 a = *(const bf16x8*)&Gb[(mt * 16 + lr) * PS + ks * 32 + kg * 8];
                        accB[mt][0] = __builtin_amdgcn_mfma_f32_16x16x32_bf16(a, b0, accB[mt][0], 0, 0, 0);
                        accB[mt][1] = __builtin_amdgcn_mfma_f32_16x16x32_bf16(a, b1, accB[mt][1], 0, 0, 0);
                    }
                }
                __syncthreads();
            }
            #pragma unroll
            for (int mt = 0; mt < 4; ++mt)
                #pragma unroll
                for (int nt = 0; nt < 2; ++nt) {
                    int col = w * 32 + nt * 16 + lr;
                    float cb = cb2[lay * CC + col];
                    #pragma unroll
                    for (int r = 0; r < 4; ++r)
                        zbuf[(mt * 16 + kg * 4 + r) * ZS + col] += accB[mt][nt][r] + cb;
                }
        }
        __syncthreads();
    }

    // ---------- masked mean over K -> zmean[n][c]
    if (t < CC) {
        float acc = 0.f, ms = 0.f;
        for (int k = 0; k < KT; ++k) {
            float mk = maskArr[k];
            ms  += mk;
            acc += zbuf[k * ZS + t] * mk;
        }
        zmean[n * CC + t] = acc / fmaxf(ms, 1.0f);
    }
}

// ---- output kernel: ragged segment mean + node_feat[seed] + final GEMM ----
__global__ __launch_bounds__(128)
void gm_out(const float* __restrict__ zmean,
            const float* __restrict__ node_feat,
            const float* __restrict__ out_W,
            const float* __restrict__ out_b,
            const int*   __restrict__ tg_idx,
            const int*   __restrict__ tg_seg,
            const int*   __restrict__ seed_ids,
            float* __restrict__ outp)
{
    __shared__ float zmL[CC], znL[CC];
    const int n = blockIdx.x;
    const int c = threadIdx.x;

    int a = 0, b = TGN;
    while (a < b) { int mm = (a + b) >> 1; if (tg_seg[mm] < n) a = mm + 1; else b = mm; }
    const int lo = a;
    int a2 = lo, b2 = TGN;
    while (a2 < b2) { int mm = (a2 + b2) >> 1; if (tg_seg[mm] < n + 1) a2 = mm + 1; else b2 = mm; }
    const int hi = a2;

    float acc = 0.f;
    for (int i = lo; i < hi; ++i) {
        int nid = tg_idx[i];
        acc += node_feat[(size_t)nid * CC + c];
    }
    float cnt = (float)(hi - lo);
    float tg  = acc / fmaxf(cnt, 1.0f);
    float zn  = tg + node_feat[(size_t)seed_ids[n] * CC + c];

    zmL[c] = zmean[n * CC + c];
    znL[c] = zn;
    __syncthreads();

    float o = out_b[c];
    for (int j = 0; j < CC; ++j) o += zmL[j] * out_W[j * 128 + c];
    for (int j = 0; j < CC; ++j) o += znL[j] * out_W[(CC + j) * 128 + c];
    outp[n * 128 + c] = o;
}

extern "C" void kernel_launch(void* const* d_in, const int* in_sizes, int n_in,
                              void* d_out, int out_size, void* d_ws, size_t ws_size,
                              hipStream_t stream)
{
    const float* edge_feat  = (const float*)d_in[0];
    const float* seed_times = (const float*)d_in[1];
    const float* nbr_time   = (const float*)d_in[2];
    const float* node_feat  = (const float*)d_in[3];
    const float* time_w     = (const float*)d_in[4];
    const float* proj_W     = (const float*)d_in[5];
    const float* proj_b     = (const float*)d_in[6];
    const float* ln1_g      = (const float*)d_in[7];
    const float* ln1_b      = (const float*)d_in[8];
    const float* tW1        = (const float*)d_in[9];
    const float* tb1        = (const float*)d_in[10];
    const float* tW2        = (const float*)d_in[11];
    const float* tb2        = (const float*)d_in[12];
    const float* ln2_g      = (const float*)d_in[13];
    const float* ln2_b      = (const float*)d_in[14];
    const float* cW1        = (const float*)d_in[15];
    const float* cb1        = (const float*)d_in[16];
    const float* cW2        = (const float*)d_in[17];
    const float* cb2        = (const float*)d_in[18];
    const float* out_W      = (const float*)d_in[19];
    const float* out_b      = (const float*)d_in[20];
    const int*   nbr_nids   = (const int*)d_in[21];
    const int*   tg_idx     = (const int*)d_in[22];
    const int*   tg_seg     = (const int*)d_in[23];
    const int*   seed_ids   = (const int*)d_in[24];

    char* ws = (char*)d_ws;
    float*          zmean   = (float*)ws;                            // 1,572,864 B
    unsigned short* projWTb = (unsigned short*)(ws + 1572864);       //    65,536 B
    unsigned short* tW1Tb   = (unsigned short*)(ws + 1638400);       //     8,192 B
    unsigned short* tW2Tb   = (unsigned short*)(ws + 1646592);       //     8,192 B
    unsigned short* cW1Tb   = (unsigned short*)(ws + 1654784);       //   262,144 B
    unsigned short* cW2Tb   = (unsigned short*)(ws + 1916928);       //   262,144 B

    gm_prep<<<1184, 256, 0, stream>>>(proj_W, tW1, tW2, cW1, cW2,
                                      projWTb, tW1Tb, tW2Tb, cW1Tb, cW2Tb);
    gm_mixer<<<NS, 256, 0, stream>>>(edge_feat, seed_times, nbr_time, time_w,
                                     proj_b, ln1_g, ln1_b, tb1, tb2, ln2_g, ln2_b,
                                     cb1, cb2, nbr_nids,
                                     projWTb, tW1Tb, tW2Tb, cW1Tb, cW2Tb, zmean);
    gm_out<<<NS, 128, 0, stream>>>(zmean, node_feat, out_W, out_b,
                                   tg_idx, tg_seg, seed_ids, (float*)d_out);
}

// Round 3
// 570.952 us; speedup vs baseline: 6.7489x; 1.1802x over previous
//
#include <hip/hip_runtime.h>
#include <math.h>

#define NS   3072
#define KT   64
#define CC   128
#define TDIM 100
#define TGN  98304
#define TH   32
#define CH   512
#define ZS   132   // zbuf fp32 stride
#define PS   136   // LNzb/Gb bf16 stride
#define PS2  264   // Ab (projection A) bf16 stride
#define PSK  72    // LNz1T stride
#define PSH  40    // G2T stride

typedef __attribute__((ext_vector_type(8))) short bf16x8;
typedef __attribute__((ext_vector_type(4))) float f32x4;

__device__ __forceinline__ unsigned short f2bf(float f) {
    unsigned int u = __float_as_uint(f);
    return (unsigned short)((u + 0x7FFFu + ((u >> 16) & 1u)) >> 16);   // RNE
}
__device__ __forceinline__ float fast_exp2(float x) {
    float r; asm("v_exp_f32 %0, %1" : "=v"(r) : "v"(x)); return r;
}
__device__ __forceinline__ float fast_rcp(float x) {
    float r; asm("v_rcp_f32 %0, %1" : "=v"(r) : "v"(x)); return r;
}
__device__ __forceinline__ float fast_cos2pi(float rev) {   // cos(2*pi*rev)
    float f = rev - floorf(rev);
    float r; asm("v_cos_f32 %0, %1" : "=v"(r) : "v"(f)); return r;
}
__device__ __forceinline__ unsigned int pk_bf16(float lo, float hi) {
    unsigned int r; asm("v_cvt_pk_bf16_f32 %0, %1, %2" : "=v"(r) : "v"(lo), "v"(hi)); return r;
}
// gelu(x) = x * sigmoid(1.5957691*(x + 0.044715 x^3)); exp2-based, ~7 VALU ops
__device__ __forceinline__ float gelu_f(float x) {
    float p = x * x;
    float e = fast_exp2(-x * fmaf(p, 0.1029436f, 2.3022082f));
    return x * fast_rcp(1.0f + e);
}

// ---- prepass: bf16-convert + transpose all weights into d_ws ------------
__global__ void gm_prep(const float* __restrict__ proj_W, const float* __restrict__ tW1,
                        const float* __restrict__ tW2, const float* __restrict__ cW1,
                        const float* __restrict__ cW2,
                        unsigned short* __restrict__ projWTb, unsigned short* __restrict__ tW1Tb,
                        unsigned short* __restrict__ tW2Tb, unsigned short* __restrict__ cW1Tb,
                        unsigned short* __restrict__ cW2Tb)
{
    int e = blockIdx.x * 256 + threadIdx.x;
    if (e < 32768) {
        int c = e >> 8, j = e & 255;
        projWTb[e] = (j < 228) ? f2bf(proj_W[j * CC + c]) : (unsigned short)0;
    }
    int e1 = e - 32768;
    if (e1 >= 0 && e1 < 4096) {           // tW1T[l][h][k]
        int l = e1 >> 11, rem = e1 & 2047, h = rem >> 6, k = rem & 63;
        tW1Tb[e1] = f2bf(tW1[(l * KT + k) * TH + h]);
    }
    int e2 = e - 36864;
    if (e2 >= 0 && e2 < 4096) {           // tW2T[l][k][h]
        int l = e2 >> 11, rem = e2 & 2047, k = rem >> 5, h = rem & 31;
        tW2Tb[e2] = f2bf(tW2[(l * TH + h) * KT + k]);
    }
    int e3 = e - 40960;
    if (e3 >= 0 && e3 < 131072) {         // cW1T[l][h][c]
        int l = e3 >> 16, rem = e3 & 65535, h = rem >> 7, c = rem & 127;
        cW1Tb[e3] = f2bf(cW1[(l * CC + c) * CH + h]);
    }
    int e4 = e - 172032;
    if (e4 >= 0 && e4 < 131072) {         // cW2T[l][c][h]
        int l = e4 >> 16, rem = e4 & 65535, c = rem >> 9, h = rem & 511;
        cW2Tb[e4] = f2bf(cW2[(l * CH + h) * CC + c]);
    }
}

// ---- main mixer: one WG (4 waves) per seed; z fp32 in LDS; MFMA everywhere
__global__ __launch_bounds__(256, 2)
void gm_mixer(const float* __restrict__ edge_feat,
              const float* __restrict__ seed_times,
              const float* __restrict__ nbr_time,
              const float* __restrict__ time_w,
              const float* __restrict__ proj_b,
              const float* __restrict__ ln1_g, const float* __restrict__ ln1_b,
              const float* __restrict__ tb1,   const float* __restrict__ tb2,
              const float* __restrict__ ln2_g, const float* __restrict__ ln2_b,
              const float* __restrict__ cb1,   const float* __restrict__ cb2,
              const int*   __restrict__ nbr_nids,
              const unsigned short* __restrict__ projWTb,
              const unsigned short* __restrict__ tW1Tb,
              const unsigned short* __restrict__ tW2Tb,
              const unsigned short* __restrict__ cW1Tb,
              const unsigned short* __restrict__ cW2Tb,
              float* __restrict__ zmean)
{
    __shared__ float zbuf[KT * ZS];          // 33,792 B residual stream (fp32)
    __shared__ short ubuf[17408];            // 34,816 B phase-union buffer
    __shared__ float mArr[KT], rArr[KT], maskArr[KT];

    const int n  = blockIdx.x;
    const int t  = threadIdx.x;
    const int w  = t >> 6;        // wave 0..3
    const int l  = t & 63;
    const int lr = l & 15;
    const int kg = l >> 4;

    const f32x4 zero4 = {0.f, 0.f, 0.f, 0.f};

    // ---------- stage dt (into mArr) + mask; edge_feat -> Ab bf16
    short* Ab = ubuf;                         // [64][PS2]
    if (t < KT) {
        mArr[t]    = seed_times[n] - nbr_time[n * KT + t];
        maskArr[t] = (nbr_nids[n * KT + t] != 0) ? 1.0f : 0.0f;
    }
    {
        const float4* ef4 = (const float4*)(edge_feat + (size_t)n * KT * CC);
        #pragma unroll
        for (int it = 0; it < 8; ++it) {
            int i4 = it * 256 + t;
            int k  = i4 >> 5;
            int c  = (i4 & 31) << 2;
            float4 v = ef4[i4];
            uint2 pk;
            pk.x = pk_bf16(v.x, v.y);
            pk.y = pk_bf16(v.z, v.w);
            *(uint2*)&Ab[k * PS2 + c] = pk;
        }
    }
    __syncthreads();
    // time features (cols 128..227), zero-pad 228..255
    for (int idx = t; idx < 4096; idx += 256) {
        int k = idx >> 6, j2 = (idx & 63) << 1;
        unsigned int pack = 0;
        if (j2 < TDIM) {
            float dt = mArr[k];
            float2 twv = *(const float2*)&time_w[j2];
            float v0 = fast_cos2pi(dt * twv.x * 0.15915494309f);
            float v1 = fast_cos2pi(dt * twv.y * 0.15915494309f);
            pack = pk_bf16(v0, v1);
        }
        *(unsigned int*)&Ab[k * PS2 + 128 + j2] = pack;
    }
    __syncthreads();

    // ---------- projection MFMA: M=64, N=128, K=256
    {
        f32x4 acc[4][2];
        #pragma unroll
        for (int mt = 0; mt < 4; ++mt) { acc[mt][0] = zero4; acc[mt][1] = zero4; }
        for (int ks = 0; ks < 8; ++ks) {
            bf16x8 b0 = *(const bf16x8*)&projWTb[(w * 32 + lr)      * 256 + ks * 32 + kg * 8];
            bf16x8 b1 = *(const bf16x8*)&projWTb[(w * 32 + 16 + lr) * 256 + ks * 32 + kg * 8];
            #pragma unroll
            for (int mt = 0; mt < 4; ++mt) {
                bf16x8 a = *(const bf16x8*)&Ab[(mt * 16 + lr) * PS2 + ks * 32 + kg * 8];
                acc[mt][0] = __builtin_amdgcn_mfma_f32_16x16x32_bf16(a, b0, acc[mt][0], 0, 0, 0);
                acc[mt][1] = __builtin_amdgcn_mfma_f32_16x16x32_bf16(a, b1, acc[mt][1], 0, 0, 0);
            }
        }
        __syncthreads();   // done with Ab before union reuse
        #pragma unroll
        for (int mt = 0; mt < 4; ++mt)
            #pragma unroll
            for (int nt = 0; nt < 2; ++nt) {
                int col = w * 32 + nt * 16 + lr;
                float pb = proj_b[col];
                #pragma unroll
                for (int r = 0; r < 4; ++r)
                    zbuf[(mt * 16 + kg * 4 + r) * ZS + col] = acc[mt][nt][r] + pb;
            }
    }
    __syncthreads();

    short* LNz1T = ubuf;               // [128][PSK] LN1(z) transposed bf16
    short* G2T   = ubuf + 128 * PSK;   // [128][PSH] token hidden transposed bf16
    short* LNzb  = ubuf;               // [64][PS]   LN2(z) bf16
    short* Gb    = ubuf + 64 * PS;     // [64][PS]   gelu chunk bf16 (row-major [m][j])

    for (int lay = 0; lay < 2; ++lay) {
        // ---------- LN1 stats
        {
            int rr = t >> 2, part = t & 3;
            const float4* zp = (const float4*)&zbuf[rr * ZS + part * 32];
            float s = 0.f, s2 = 0.f;
            #pragma unroll
            for (int i = 0; i < 8; ++i) {
                float4 v = zp[i];
                s  += v.x + v.y + v.z + v.w;
                s2 += v.x * v.x + v.y * v.y + v.z * v.z + v.w * v.w;
            }
            s += __shfl_xor(s, 1); s2 += __shfl_xor(s2, 1);
            s += __shfl_xor(s, 2); s2 += __shfl_xor(s2, 2);
            if (part == 0) {
                float m = s * (1.0f / CC);
                float var = s2 * (1.0f / CC) - m * m;
                mArr[rr] = m; rArr[rr] = rsqrtf(var + 1e-5f);
            }
        }
        __syncthreads();

        // ---------- LNz1T materialize: LNz1T[c][k]  (k = lane, row-wise float2 reads)
        {
            const float* g1 = ln1_g + lay * CC;
            const float* b1 = ln1_b + lay * CC;
            const int kk = l;   // 0..63
            const float mk = mArr[kk], rk = rArr[kk];
            #pragma unroll
            for (int it = 0; it < 16; ++it) {
                int c = w * 2 + it * 8;
                float2 zv = *(const float2*)&zbuf[kk * ZS + c];
                float v0 = (zv.x - mk) * rk * g1[c]     + b1[c];
                float v1 = (zv.y - mk) * rk * g1[c + 1] + b1[c + 1];
                unsigned int pk = pk_bf16(v0, v1);
                LNz1T[c * PSK + kk]       = (short)(pk & 0xFFFFu);
                LNz1T[(c + 1) * PSK + kk] = (short)(pk >> 16);
            }
        }
        __syncthreads();

        // ---------- token mix 1 MFMA: C[hh][c], packed b64 store into G2T[c][hh]
        {
            f32x4 acc1[2][2];
            #pragma unroll
            for (int mt = 0; mt < 2; ++mt) { acc1[mt][0] = zero4; acc1[mt][1] = zero4; }
            #pragma unroll
            for (int ks = 0; ks < 2; ++ks) {
                bf16x8 bb0 = *(const bf16x8*)&LNz1T[(w * 32 + lr)      * PSK + ks * 32 + kg * 8];
                bf16x8 bb1 = *(const bf16x8*)&LNz1T[(w * 32 + 16 + lr) * PSK + ks * 32 + kg * 8];
                #pragma unroll
                for (int mt = 0; mt < 2; ++mt) {
                    bf16x8 a = *(const bf16x8*)&tW1Tb[lay * 2048 + (mt * 16 + lr) * 64 + ks * 32 + kg * 8];
                    acc1[mt][0] = __builtin_amdgcn_mfma_f32_16x16x32_bf16(a, bb0, acc1[mt][0], 0, 0, 0);
                    acc1[mt][1] = __builtin_amdgcn_mfma_f32_16x16x32_bf16(a, bb1, acc1[mt][1], 0, 0, 0);
                }
            }
            #pragma unroll
            for (int mt = 0; mt < 2; ++mt) {
                float4 tbv = *(const float4*)&tb1[lay * TH + mt * 16 + kg * 4];
                #pragma unroll
                for (int nt = 0; nt < 2; ++nt) {
                    int col = w * 32 + nt * 16 + lr;
                    float g0 = gelu_f(acc1[mt][nt][0] + tbv.x);
                    float g1v = gelu_f(acc1[mt][nt][1] + tbv.y);
                    float g2 = gelu_f(acc1[mt][nt][2] + tbv.z);
                    float g3 = gelu_f(acc1[mt][nt][3] + tbv.w);
                    uint2 pk;
                    pk.x = pk_bf16(g0, g1v);
                    pk.y = pk_bf16(g2, g3);
                    *(uint2*)&G2T[col * PSH + mt * 16 + kg * 4] = pk;
                }
            }
        }
        // no barrier: wave w wrote exactly the G2T cols it reads below
        // ---------- token mix 2 MFMA: M=64(k), N=128(c), K=32 + residual
        {
            f32x4 acc2[4][2];
            #pragma unroll
            for (int mt = 0; mt < 4; ++mt) { acc2[mt][0] = zero4; acc2[mt][1] = zero4; }
            bf16x8 bb0 = *(const bf16x8*)&G2T[(w * 32 + lr)      * PSH + kg * 8];
            bf16x8 bb1 = *(const bf16x8*)&G2T[(w * 32 + 16 + lr) * PSH + kg * 8];
            #pragma unroll
            for (int mt = 0; mt < 4; ++mt) {
                bf16x8 a = *(const bf16x8*)&tW2Tb[lay * 2048 + (mt * 16 + lr) * 32 + kg * 8];
                acc2[mt][0] = __builtin_amdgcn_mfma_f32_16x16x32_bf16(a, bb0, acc2[mt][0], 0, 0, 0);
                acc2[mt][1] = __builtin_amdgcn_mfma_f32_16x16x32_bf16(a, bb1, acc2[mt][1], 0, 0, 0);
            }
            #pragma unroll
            for (int mt = 0; mt < 4; ++mt)
                #pragma unroll
                for (int nt = 0; nt < 2; ++nt) {
                    int col = w * 32 + nt * 16 + lr;
                    #pragma unroll
                    for (int r = 0; r < 4; ++r) {
                        int row = mt * 16 + kg * 4 + r;
                        zbuf[row * ZS + col] += acc2[mt][nt][r] + tb2[lay * KT + row];
                    }
                }
        }
        __syncthreads();

        // ---------- LN2 stats
        {
            int rr = t >> 2, part = t & 3;
            const float4* zp = (const float4*)&zbuf[rr * ZS + part * 32];
            float s = 0.f, s2 = 0.f;
            #pragma unroll
            for (int i = 0; i < 8; ++i) {
                float4 v = zp[i];
                s  += v.x + v.y + v.z + v.w;
                s2 += v.x * v.x + v.y * v.y + v.z * v.z + v.w * v.w;
            }
            s += __shfl_xor(s, 1); s2 += __shfl_xor(s2, 1);
            s += __shfl_xor(s, 2); s2 += __shfl_xor(s2, 2);
            if (part == 0) {
                float m = s * (1.0f / CC);
                float var = s2 * (1.0f / CC) - m * m;
                mArr[rr] = m; rArr[rr] = rsqrtf(var + 1e-5f);
            }
        }
        __syncthreads();

        // ---------- LNzb materialize: LNzb[k][c]
        {
            const float* g2 = ln2_g + lay * CC;
            const float* b2 = ln2_b + lay * CC;
            for (int idx = t; idx < 4096; idx += 256) {
                int k = idx >> 6, c2 = (idx & 63) << 1;
                float m = mArr[k], r = rArr[k];
                float v0 = (zbuf[k * ZS + c2]     - m) * r * g2[c2]     + b2[c2];
                float v1 = (zbuf[k * ZS + c2 + 1] - m) * r * g2[c2 + 1] + b2[c2 + 1];
                *(unsigned int*)&LNzb[k * PS + c2] = pk_bf16(v0, v1);
            }
        }
        __syncthreads();

        // ---------- channel mix: 4 hidden chunks of 128
        {
            f32x4 accB[4][2];
            #pragma unroll
            for (int mt = 0; mt < 4; ++mt) { accB[mt][0] = zero4; accB[mt][1] = zero4; }

            for (int jc = 0; jc < 4; ++jc) {
                // phase A (swapped operands): CT[j][m] -> b64-contiguous store into Gb[m][j]
                f32x4 accA[4][2];
                #pragma unroll
                for (int mt = 0; mt < 4; ++mt) { accA[mt][0] = zero4; accA[mt][1] = zero4; }
                #pragma unroll
                for (int ks = 0; ks < 4; ++ks) {
                    const unsigned short* w1p = cW1Tb + lay * CH * CC
                                              + (jc * 128 + w * 32 + lr) * CC + ks * 32 + kg * 8;
                    bf16x8 a0 = *(const bf16x8*)w1p;
                    bf16x8 a1 = *(const bf16x8*)(w1p + 16 * CC);
                    #pragma unroll
                    for (int mt = 0; mt < 4; ++mt) {
                        bf16x8 b = *(const bf16x8*)&LNzb[(mt * 16 + lr) * PS + ks * 32 + kg * 8];
                        accA[mt][0] = __builtin_amdgcn_mfma_f32_16x16x32_bf16(a0, b, accA[mt][0], 0, 0, 0);
                        accA[mt][1] = __builtin_amdgcn_mfma_f32_16x16x32_bf16(a1, b, accA[mt][1], 0, 0, 0);
                    }
                }
                #pragma unroll
                for (int nt = 0; nt < 2; ++nt) {
                    int j0 = w * 32 + nt * 16 + kg * 4;
                    float4 cbv = *(const float4*)&cb1[lay * CH + jc * 128 + j0];
                    #pragma unroll
                    for (int mt = 0; mt < 4; ++mt) {
                        float g0 = gelu_f(accA[mt][nt][0] + cbv.x);
                        float g1v = gelu_f(accA[mt][nt][1] + cbv.y);
                        float g2 = gelu_f(accA[mt][nt][2] + cbv.z);
                        float g3 = gelu_f(accA[mt][nt][3] + cbv.w);
                        uint2 pk;
                        pk.x = pk_bf16(g0, g1v);
                        pk.y = pk_bf16(g2, g3);
                        *(uint2*)&Gb[(mt * 16 + lr) * PS + j0] = pk;
                    }
                }
                __syncthreads();
                // phase B: accB += G @ cW2[chunk, :]
                #pragma unroll
                for (int ks = 0; ks < 4; ++ks) {
                    const unsigned short* w2p = cW2Tb + lay * CC * CH
                                              + (w * 32 + lr) * CH + jc * 128 + ks * 32 + kg * 8;
                    bf16x8 b0 = *(const bf16x8*)w2p;
                    bf16x8 b1 = *(const bf16x8*)(w2p + 16 * CH);
                    #pragma unroll
                    for (int mt = 0; mt < 4; ++mt) {
                        bf16x8 a = *(const bf16x8*)&Gb[(mt * 16 + lr) * PS + ks * 32 + kg * 8];
                        accB[mt][0] = __builtin_amdgcn_mfma_f32_16x16x32_bf16(a, b0, accB[mt][0], 0, 0, 0);
                        accB[mt][1] = __builtin_amdgcn_mfma_f32_16x16x32_bf16(a, b1, accB[mt][1], 0, 0, 0);
                    }
                }
                __syncthreads();
            }
            #pragma unroll
            for (int mt = 0; mt < 4; ++mt)
                #pragma unroll
                for (int nt = 0; nt < 2; ++nt) {
                    int col = w * 32 + nt * 16 + lr;
                    float cb = cb2[lay * CC + col];
                    #pragma unroll
                    for (int r = 0; r < 4; ++r)
                        zbuf[(mt * 16 + kg * 4 + r) * ZS + col] += accB[mt][nt][r] + cb;
                }
        }
        __syncthreads();
    }

    // ---------- masked mean over K -> zmean[n][c] (256 threads)
    {
        float* red = (float*)ubuf;
        const int c = t & 127, h = t >> 7;
        float acc = 0.f, ms = 0.f;
        for (int k = h * 32; k < h * 32 + 32; ++k) {
            float mk = maskArr[k];
            ms  += mk;
            acc += zbuf[k * ZS + c] * mk;
        }
        red[h * 128 + c] = acc;
        red[256 + h * 128 + c] = ms;
        __syncthreads();
        if (t < CC) {
            float tot  = red[t] + red[128 + t];
            float mtot = red[256 + t] + red[384 + t];
            zmean[n * CC + t] = tot / fmaxf(mtot, 1.0f);
        }
    }
}

// ---- output kernel: ragged segment mean + node_feat[seed] + final GEMM ----
__global__ __launch_bounds__(256)
void gm_out(const float* __restrict__ zmean,
            const float* __restrict__ node_feat,
            const float* __restrict__ out_W,
            const float* __restrict__ out_b,
            const int*   __restrict__ tg_idx,
            const int*   __restrict__ tg_seg,
            const int*   __restrict__ seed_ids,
            float* __restrict__ outp)
{
    __shared__ float redf[8 * 132];
    __shared__ float zmL[CC], znL[CC], oL[2 * CC];
    const int n = blockIdx.x;
    const int t = threadIdx.x;
    const int q = t & 31, g = t >> 5;

    int a = 0, b = TGN;
    while (a < b) { int mm = (a + b) >> 1; if (tg_seg[mm] < n) a = mm + 1; else b = mm; }
    const int lo = a;
    int a2 = lo, b2 = TGN;
    while (a2 < b2) { int mm = (a2 + b2) >> 1; if (tg_seg[mm] < n + 1) a2 = mm + 1; else b2 = mm; }
    const int hi = a2;

    float4 acc = {0.f, 0.f, 0.f, 0.f};
    for (int i = lo + g; i < hi; i += 8) {
        int nid = tg_idx[i];
        const float4* nf = (const float4*)(node_feat + (size_t)nid * CC);
        float4 v = nf[q];
        acc.x += v.x; acc.y += v.y; acc.z += v.z; acc.w += v.w;
    }
    *(float4*)&redf[g * 132 + q * 4] = acc;
    __syncthreads();
    if (t < CC) {
        float s = 0.f;
        #pragma unroll
        for (int gg = 0; gg < 8; ++gg) s += redf[gg * 132 + t];
        float cnt = (float)(hi - lo);
        znL[t] = s / fmaxf(cnt, 1.0f) + node_feat[(size_t)seed_ids[n] * CC + t];
        zmL[t] = zmean[n * CC + t];
    }
    __syncthreads();
    {
        const int c = t & 127, h = t >> 7;
        const float* src = h ? znL : zmL;
        const float* Wp  = out_W + (size_t)h * CC * 128;
        float o = 0.f;
        for (int j = 0; j < CC; ++j) o += src[j] * Wp[j * 128 + c];
        oL[h * 128 + c] = o;
    }
    __syncthreads();
    if (t < CC) outp[n * 128 + t] = oL[t] + oL[CC + t] + out_b[t];
}

extern "C" void kernel_launch(void* const* d_in, const int* in_sizes, int n_in,
                              void* d_out, int out_size, void* d_ws, size_t ws_size,
                              hipStream_t stream)
{
    const float* edge_feat  = (const float*)d_in[0];
    const float* seed_times = (const float*)d_in[1];
    const float* nbr_time   = (const float*)d_in[2];
    const float* node_feat  = (const float*)d_in[3];
    const float* time_w     = (const float*)d_in[4];
    const float* proj_W     = (const float*)d_in[5];
    const float* proj_b     = (const float*)d_in[6];
    const float* ln1_g      = (const float*)d_in[7];
    const float* ln1_b      = (const float*)d_in[8];
    const float* tW1        = (const float*)d_in[9];
    const float* tb1        = (const float*)d_in[10];
    const float* tW2        = (const float*)d_in[11];
    const float* tb2        = (const float*)d_in[12];
    const float* ln2_g      = (const float*)d_in[13];
    const float* ln2_b      = (const float*)d_in[14];
    const float* cW1        = (const float*)d_in[15];
    const float* cb1        = (const float*)d_in[16];
    const float* cW2        = (const float*)d_in[17];
    const float* cb2        = (const float*)d_in[18];
    const float* out_W      = (const float*)d_in[19];
    const float* out_b      = (const float*)d_in[20];
    const int*   nbr_nids   = (const int*)d_in[21];
    const int*   tg_idx     = (const int*)d_in[22];
    const int*   tg_seg     = (const int*)d_in[23];
    const int*   seed_ids   = (const int*)d_in[24];

    char* ws = (char*)d_ws;
    float*          zmean   = (float*)ws;                            // 1,572,864 B
    unsigned short* projWTb = (unsigned short*)(ws + 1572864);       //    65,536 B
    unsigned short* tW1Tb   = (unsigned short*)(ws + 1638400);       //     8,192 B
    unsigned short* tW2Tb   = (unsigned short*)(ws + 1646592);       //     8,192 B
    unsigned short* cW1Tb   = (unsigned short*)(ws + 1654784);       //   262,144 B
    unsigned short* cW2Tb   = (unsigned short*)(ws + 1916928);       //   262,144 B

    gm_prep<<<1184, 256, 0, stream>>>(proj_W, tW1, tW2, cW1, cW2,
                                      projWTb, tW1Tb, tW2Tb, cW1Tb, cW2Tb);
    gm_mixer<<<NS, 256, 0, stream>>>(edge_feat, seed_times, nbr_time, time_w,
                                     proj_b, ln1_g, ln1_b, tb1, tb2, ln2_g, ln2_b,
                                     cb1, cb2, nbr_nids,
                                     projWTb, tW1Tb, tW2Tb, cW1Tb, cW2Tb, zmean);
    gm_out<<<NS, 256, 0, stream>>>(zmean, node_feat, out_W, out_b,
                                   tg_idx, tg_seg, seed_ids, (float*)d_out);
}

// Round 4
// 524.012 us; speedup vs baseline: 7.3534x; 1.0896x over previous
//
#include <hip/hip_runtime.h>
#include <math.h>

#define NS   3072
#define KT   64
#define CC   128
#define TDIM 100
#define TGN  98304
#define TH   32
#define CH   512
#define PS   136   // LNzb/Gb bf16 stride (272 B rows, 16B-aligned)
#define PSA  136   // Ab half-K stride
#define PSK  72    // LNz1T stride (144 B)
#define PSH  40    // G2T stride (80 B)

typedef __attribute__((ext_vector_type(8))) short bf16x8;
typedef __attribute__((ext_vector_type(4))) float f32x4;

__device__ __forceinline__ unsigned short f2bf(float f) {
    unsigned int u = __float_as_uint(f);
    return (unsigned short)((u + 0x7FFFu + ((u >> 16) & 1u)) >> 16);   // RNE
}
__device__ __forceinline__ float fast_exp2(float x) {
    float r; asm("v_exp_f32 %0, %1" : "=v"(r) : "v"(x)); return r;
}
__device__ __forceinline__ float fast_rcp(float x) {
    float r; asm("v_rcp_f32 %0, %1" : "=v"(r) : "v"(x)); return r;
}
__device__ __forceinline__ float fast_cos2pi(float rev) {   // cos(2*pi*rev)
    float f = rev - floorf(rev);
    float r; asm("v_cos_f32 %0, %1" : "=v"(r) : "v"(f)); return r;
}
__device__ __forceinline__ unsigned int pk_bf16(float lo, float hi) {
    unsigned int r; asm("v_cvt_pk_bf16_f32 %0, %1, %2" : "=v"(r) : "v"(lo), "v"(hi)); return r;
}
__device__ __forceinline__ float gelu_f(float x) {
    float p = x * x;
    float e = fast_exp2(-x * fmaf(p, 0.1029436f, 2.3022082f));
    return x * fast_rcp(1.0f + e);
}

// ---- tiled transposes (coalesced both sides): cW1, cW2, proj_W -----------
__global__ __launch_bounds__(256)
void gm_trans(const float* __restrict__ cW1, const float* __restrict__ cW2,
              const float* __restrict__ proj_W,
              unsigned short* __restrict__ cW1Tb, unsigned short* __restrict__ cW2Tb,
              unsigned short* __restrict__ projWTb)
{
    __shared__ float tile[32][33];
    const int bid = blockIdx.x;
    const float* src; unsigned short* dst;
    int R, Cs, oC, tr, tc;
    if (bid < 128) {            // cW1 [l][128][512] -> [l][512][128]
        int l = bid >> 6, q = bid & 63; tr = q >> 4; tc = q & 15;
        src = cW1 + l * CC * CH; dst = cW1Tb + l * CH * CC; R = CC; Cs = CH; oC = CC;
    } else if (bid < 256) {     // cW2 [l][512][128] -> [l][128][512]
        int b = bid - 128, l = b >> 6, q = b & 63; tr = q & 15; tc = q >> 4;
        src = cW2 + l * CH * CC; dst = cW2Tb + l * CC * CH; R = CH; Cs = CC; oC = CH;
    } else {                    // proj_W [228][128] -> [128][256] (zero-pad rows>=228)
        int b = bid - 256; tr = b >> 2; tc = b & 3;
        src = proj_W; dst = projWTb; R = 228; Cs = CC; oC = 256;
    }
    const int tx = threadIdx.x & 31, ty0 = threadIdx.x >> 5;
    #pragma unroll
    for (int i = 0; i < 4; ++i) {
        int ty = ty0 + i * 8;
        int rr = tr * 32 + ty, cc = tc * 32 + tx;
        tile[ty][tx] = (rr < R) ? src[rr * Cs + cc] : 0.0f;
    }
    __syncthreads();
    #pragma unroll
    for (int i = 0; i < 4; ++i) {
        int ty = ty0 + i * 8;
        int orow = tc * 32 + ty, ocol = tr * 32 + tx;
        dst[orow * oC + ocol] = f2bf(tile[tx][ty]);
    }
}

__global__ __launch_bounds__(256)
void gm_prep_small(const float* __restrict__ tW1, const float* __restrict__ tW2,
                   unsigned short* __restrict__ tW1Tb, unsigned short* __restrict__ tW2Tb)
{
    int e = blockIdx.x * 256 + threadIdx.x;   // 0..8191
    if (e < 4096) {           // tW1T[l][h][k]
        int l = e >> 11, rem = e & 2047, h = rem >> 6, k = rem & 63;
        tW1Tb[e] = f2bf(tW1[(l * KT + k) * TH + h]);
    } else {                  // tW2T[l][k][h]
        int e2 = e - 4096, l = e2 >> 11, rem = e2 & 2047, k = rem >> 5, h = rem & 31;
        tW2Tb[e2] = f2bf(tW2[(l * TH + h) * KT + k]);
    }
}

// ---- main mixer: z residual entirely in registers; LDS = staging only ----
__global__ __launch_bounds__(256, 3)
void gm_mixer(const float* __restrict__ edge_feat,
              const float* __restrict__ seed_times,
              const float* __restrict__ nbr_time,
              const float* __restrict__ time_w,
              const float* __restrict__ proj_b,
              const float* __restrict__ ln1_g, const float* __restrict__ ln1_b,
              const float* __restrict__ tb1,   const float* __restrict__ tb2,
              const float* __restrict__ ln2_g, const float* __restrict__ ln2_b,
              const float* __restrict__ cb1,   const float* __restrict__ cb2,
              const int*   __restrict__ nbr_nids,
              const unsigned short* __restrict__ projWTb,
              const unsigned short* __restrict__ tW1Tb,
              const unsigned short* __restrict__ tW2Tb,
              const unsigned short* __restrict__ cW1Tb,
              const unsigned short* __restrict__ cW2Tb,
              float* __restrict__ zmean)
{
    __shared__ short ubuf[17408];                  // 34,816 B phase-union
    __shared__ float lnS[256], lnS2[256];          //  2,048 B LN partials
    __shared__ float mArr[KT], rArr[KT], maskArr[KT], dtArr[KT];

    const int n  = blockIdx.x;
    const int t  = threadIdx.x;
    const int w  = t >> 6;
    const int l  = t & 63;
    const int lr = l & 15;
    const int kg = l >> 4;
    const int c0 = w * 32 + lr;
    const int c1 = c0 + 16;

    short* Ab    = ubuf;               // [64][PSA]  projection A (half-K)
    short* LNz1T = ubuf;               // [128][PSK] LN1(z)^T
    short* G2T   = ubuf + 128 * PSK;   // [128][PSH] token hidden^T
    short* LNzb  = ubuf;               // [64][PS]   LN2(z)
    short* Gb    = ubuf + 64 * PS;     // [64][PS]   gelu chunk

    const f32x4 zero4 = {0.f, 0.f, 0.f, 0.f};
    f32x4 zr[4][2];                    // residual stream z, fp32, C-fragment layout

    if (t < KT) {
        dtArr[t]   = seed_times[n] - nbr_time[n * KT + t];
        maskArr[t] = (nbr_nids[n * KT + t] != 0) ? 1.0f : 0.0f;
    }
    // stage Ab pass1: edge_feat (K cols 0..127)
    {
        const float4* ef4 = (const float4*)(edge_feat + (size_t)n * KT * CC);
        #pragma unroll
        for (int it = 0; it < 8; ++it) {
            int i4 = it * 256 + t;
            int k = i4 >> 5, c = (i4 & 31) << 2;
            float4 v = ef4[i4];
            uint2 pk; pk.x = pk_bf16(v.x, v.y); pk.y = pk_bf16(v.z, v.w);
            *(uint2*)&Ab[k * PSA + c] = pk;
        }
    }
    __syncthreads();

    // ---------- projection: M=64, N=128, K=256 in two half-K passes
    {
        f32x4 acc[4][2];
        #pragma unroll
        for (int mt = 0; mt < 4; ++mt) { acc[mt][0] = zero4; acc[mt][1] = zero4; }
        #pragma unroll
        for (int p = 0; p < 2; ++p) {
            #pragma unroll
            for (int ks = 0; ks < 4; ++ks) {
                const unsigned short* bp = projWTb + (w * 32 + lr) * 256 + p * 128 + ks * 32 + kg * 8;
                bf16x8 b0 = *(const bf16x8*)bp;
                bf16x8 b1 = *(const bf16x8*)(bp + 16 * 256);
                #pragma unroll
                for (int mt = 0; mt < 4; ++mt) {
                    bf16x8 a = *(const bf16x8*)&Ab[(mt * 16 + lr) * PSA + ks * 32 + kg * 8];
                    acc[mt][0] = __builtin_amdgcn_mfma_f32_16x16x32_bf16(a, b0, acc[mt][0], 0, 0, 0);
                    acc[mt][1] = __builtin_amdgcn_mfma_f32_16x16x32_bf16(a, b1, acc[mt][1], 0, 0, 0);
                }
            }
            if (p == 0) {
                __syncthreads();        // all waves done reading Ab pass1
                // stage Ab pass2: time features (K cols 128..227 -> local 0..99, pad->127)
                #pragma unroll
                for (int it = 0; it < 16; ++it) {
                    int idx = it * 256 + t;
                    int k = idx >> 6, j2 = (idx & 63) << 1;
                    unsigned pk = 0;
                    if (j2 < TDIM) {
                        float dt = dtArr[k];
                        float2 twv = *(const float2*)&time_w[j2];
                        pk = pk_bf16(fast_cos2pi(dt * twv.x * 0.15915494309f),
                                     fast_cos2pi(dt * twv.y * 0.15915494309f));
                    }
                    *(unsigned*)&Ab[k * PSA + j2] = pk;
                }
                __syncthreads();
            }
        }
        #pragma unroll
        for (int mt = 0; mt < 4; ++mt)
            #pragma unroll
            for (int nt = 0; nt < 2; ++nt) {
                float pb = proj_b[nt ? c1 : c0];
                #pragma unroll
                for (int r = 0; r < 4; ++r) zr[mt][nt][r] = acc[mt][nt][r] + pb;
            }
    }

    for (int lay = 0; lay < 2; ++lay) {
        // ---------- LN1 stats: butterfly over lr + cross-wave LDS combine
        #pragma unroll
        for (int mt = 0; mt < 4; ++mt) {
            f32x4 sv, qv;
            #pragma unroll
            for (int r = 0; r < 4; ++r) {
                float z0 = zr[mt][0][r], z1 = zr[mt][1][r];
                sv[r] = z0 + z1;
                qv[r] = z0 * z0 + z1 * z1;
            }
            #pragma unroll
            for (int d = 1; d < 16; d <<= 1)
                #pragma unroll
                for (int r = 0; r < 4; ++r) {
                    sv[r] += __shfl_xor(sv[r], d);
                    qv[r] += __shfl_xor(qv[r], d);
                }
            if (lr == 0) {
                *(f32x4*)&lnS [w * 64 + mt * 16 + kg * 4] = sv;
                *(f32x4*)&lnS2[w * 64 + mt * 16 + kg * 4] = qv;
            }
        }
        __syncthreads();
        if (t < KT) {
            float s  = lnS [t] + lnS [64 + t] + lnS [128 + t] + lnS [192 + t];
            float s2 = lnS2[t] + lnS2[64 + t] + lnS2[128 + t] + lnS2[192 + t];
            float m = s * (1.0f / CC);
            float var = s2 * (1.0f / CC) - m * m;
            mArr[t] = m; rArr[t] = rsqrtf(var + 1e-5f);
        }
        __syncthreads();

        // ---------- LNz1T[c][k] from registers (wave-local c rows)
        {
            const float* g1 = ln1_g + lay * CC;
            const float* b1 = ln1_b + lay * CC;
            float gc0 = g1[c0], bc0 = b1[c0], gc1 = g1[c1], bc1 = b1[c1];
            #pragma unroll
            for (int mt = 0; mt < 4; ++mt) {
                f32x4 mv = *(const f32x4*)&mArr[mt * 16 + kg * 4];
                f32x4 rv = *(const f32x4*)&rArr[mt * 16 + kg * 4];
                #pragma unroll
                for (int nt = 0; nt < 2; ++nt) {
                    float gg = nt ? gc1 : gc0, bb = nt ? bc1 : bc0;
                    int c = nt ? c1 : c0;
                    float v0 = (zr[mt][nt][0] - mv[0]) * rv[0] * gg + bb;
                    float v1 = (zr[mt][nt][1] - mv[1]) * rv[1] * gg + bb;
                    float v2 = (zr[mt][nt][2] - mv[2]) * rv[2] * gg + bb;
                    float v3 = (zr[mt][nt][3] - mv[3]) * rv[3] * gg + bb;
                    uint2 pk; pk.x = pk_bf16(v0, v1); pk.y = pk_bf16(v2, v3);
                    *(uint2*)&LNz1T[c * PSK + mt * 16 + kg * 4] = pk;
                }
            }
        }
        // no barrier: token mix is fully wave-local in c

        // ---------- token mix 1: C[hh][c] -> gelu -> G2T[c][hh]
        {
            f32x4 acc1[2][2];
            #pragma unroll
            for (int mt = 0; mt < 2; ++mt) { acc1[mt][0] = zero4; acc1[mt][1] = zero4; }
            #pragma unroll
            for (int ks = 0; ks < 2; ++ks) {
                bf16x8 bb0 = *(const bf16x8*)&LNz1T[c0 * PSK + ks * 32 + kg * 8];
                bf16x8 bb1 = *(const bf16x8*)&LNz1T[c1 * PSK + ks * 32 + kg * 8];
                #pragma unroll
                for (int mt = 0; mt < 2; ++mt) {
                    bf16x8 a = *(const bf16x8*)&tW1Tb[lay * 2048 + (mt * 16 + lr) * 64 + ks * 32 + kg * 8];
                    acc1[mt][0] = __builtin_amdgcn_mfma_f32_16x16x32_bf16(a, bb0, acc1[mt][0], 0, 0, 0);
                    acc1[mt][1] = __builtin_amdgcn_mfma_f32_16x16x32_bf16(a, bb1, acc1[mt][1], 0, 0, 0);
                }
            }
            #pragma unroll
            for (int mt = 0; mt < 2; ++mt) {
                float4 tbv = *(const float4*)&tb1[lay * TH + mt * 16 + kg * 4];
                #pragma unroll
                for (int nt = 0; nt < 2; ++nt) {
                    int c = nt ? c1 : c0;
                    float g0 = gelu_f(acc1[mt][nt][0] + tbv.x);
                    float g1v = gelu_f(acc1[mt][nt][1] + tbv.y);
                    float g2 = gelu_f(acc1[mt][nt][2] + tbv.z);
                    float g3 = gelu_f(acc1[mt][nt][3] + tbv.w);
                    uint2 pk; pk.x = pk_bf16(g0, g1v); pk.y = pk_bf16(g2, g3);
                    *(uint2*)&G2T[c * PSH + mt * 16 + kg * 4] = pk;
                }
            }
        }
        // ---------- token mix 2: z += C (registers)
        {
            bf16x8 bb0 = *(const bf16x8*)&G2T[c0 * PSH + kg * 8];
            bf16x8 bb1 = *(const bf16x8*)&G2T[c1 * PSH + kg * 8];
            #pragma unroll
            for (int mt = 0; mt < 4; ++mt) {
                f32x4 a2v0 = zero4, a2v1 = zero4;
                bf16x8 a = *(const bf16x8*)&tW2Tb[lay * 2048 + (mt * 16 + lr) * 32 + kg * 8];
                a2v0 = __builtin_amdgcn_mfma_f32_16x16x32_bf16(a, bb0, a2v0, 0, 0, 0);
                a2v1 = __builtin_amdgcn_mfma_f32_16x16x32_bf16(a, bb1, a2v1, 0, 0, 0);
                float4 t2v = *(const float4*)&tb2[lay * KT + mt * 16 + kg * 4];
                #pragma unroll
                for (int r = 0; r < 4; ++r) {
                    float tb = (r == 0) ? t2v.x : (r == 1) ? t2v.y : (r == 2) ? t2v.z : t2v.w;
                    zr[mt][0][r] += a2v0[r] + tb;
                    zr[mt][1][r] += a2v1[r] + tb;
                }
            }
        }

        // ---------- LN2 stats (same scheme)
        #pragma unroll
        for (int mt = 0; mt < 4; ++mt) {
            f32x4 sv, qv;
            #pragma unroll
            for (int r = 0; r < 4; ++r) {
                float z0 = zr[mt][0][r], z1 = zr[mt][1][r];
                sv[r] = z0 + z1;
                qv[r] = z0 * z0 + z1 * z1;
            }
            #pragma unroll
            for (int d = 1; d < 16; d <<= 1)
                #pragma unroll
                for (int r = 0; r < 4; ++r) {
                    sv[r] += __shfl_xor(sv[r], d);
                    qv[r] += __shfl_xor(qv[r], d);
                }
            if (lr == 0) {
                *(f32x4*)&lnS [w * 64 + mt * 16 + kg * 4] = sv;
                *(f32x4*)&lnS2[w * 64 + mt * 16 + kg * 4] = qv;
            }
        }
        __syncthreads();
        if (t < KT) {
            float s  = lnS [t] + lnS [64 + t] + lnS [128 + t] + lnS [192 + t];
            float s2 = lnS2[t] + lnS2[64 + t] + lnS2[128 + t] + lnS2[192 + t];
            float m = s * (1.0f / CC);
            float var = s2 * (1.0f / CC) - m * m;
            mArr[t] = m; rArr[t] = rsqrtf(var + 1e-5f);
        }
        __syncthreads();

        // ---------- LNzb[k][c] from registers (lane-pair packed b32 writes)
        {
            const float* g2 = ln2_g + lay * CC;
            const float* b2 = ln2_b + lay * CC;
            float gc0 = g2[c0], bc0 = b2[c0], gc1 = g2[c1], bc1 = b2[c1];
            const bool odd = lr & 1;
            const int cb = odd ? (c1 - 1) : c0;
            #pragma unroll
            for (int mt = 0; mt < 4; ++mt) {
                f32x4 mv = *(const f32x4*)&mArr[mt * 16 + kg * 4];
                f32x4 rv = *(const f32x4*)&rArr[mt * 16 + kg * 4];
                #pragma unroll
                for (int r = 0; r < 4; ++r) {
                    float v0 = (zr[mt][0][r] - mv[r]) * rv[r] * gc0 + bc0;
                    float v1 = (zr[mt][1][r] - mv[r]) * rv[r] * gc1 + bc1;
                    float s0 = __shfl_xor(v0, 1);
                    float s1 = __shfl_xor(v1, 1);
                    unsigned pka = pk_bf16(v0, s0);
                    unsigned pkb = pk_bf16(s1, v1);
                    unsigned pkv = odd ? pkb : pka;
                    *(unsigned*)&LNzb[(mt * 16 + kg * 4 + r) * PS + cb] = pkv;
                }
            }
        }
        __syncthreads();   // LNzb is read cross-wave

        // ---------- channel mix: 4 hidden chunks of 128
        {
            f32x4 accB[4][2];
            #pragma unroll
            for (int mt = 0; mt < 4; ++mt) { accB[mt][0] = zero4; accB[mt][1] = zero4; }

            for (int jc = 0; jc < 4; ++jc) {
                f32x4 accA[4][2];
                #pragma unroll
                for (int mt = 0; mt < 4; ++mt) { accA[mt][0] = zero4; accA[mt][1] = zero4; }
                #pragma unroll
                for (int ks = 0; ks < 4; ++ks) {
                    const unsigned short* w1p = cW1Tb + lay * CH * CC
                                              + (jc * 128 + w * 32 + lr) * CC + ks * 32 + kg * 8;
                    bf16x8 a0 = *(const bf16x8*)w1p;
                    bf16x8 a1 = *(const bf16x8*)(w1p + 16 * CC);
                    #pragma unroll
                    for (int mt = 0; mt < 4; ++mt) {
                        bf16x8 b = *(const bf16x8*)&LNzb[(mt * 16 + lr) * PS + ks * 32 + kg * 8];
                        accA[mt][0] = __builtin_amdgcn_mfma_f32_16x16x32_bf16(a0, b, accA[mt][0], 0, 0, 0);
                        accA[mt][1] = __builtin_amdgcn_mfma_f32_16x16x32_bf16(a1, b, accA[mt][1], 0, 0, 0);
                    }
                }
                #pragma unroll
                for (int nt = 0; nt < 2; ++nt) {
                    int j0 = w * 32 + nt * 16 + kg * 4;
                    float4 cbv = *(const float4*)&cb1[lay * CH + jc * 128 + j0];
                    #pragma unroll
                    for (int mt = 0; mt < 4; ++mt) {
                        float g0 = gelu_f(accA[mt][nt][0] + cbv.x);
                        float g1v = gelu_f(accA[mt][nt][1] + cbv.y);
                        float g2 = gelu_f(accA[mt][nt][2] + cbv.z);
                        float g3 = gelu_f(accA[mt][nt][3] + cbv.w);
                        uint2 pk; pk.x = pk_bf16(g0, g1v); pk.y = pk_bf16(g2, g3);
                        *(uint2*)&Gb[(mt * 16 + lr) * PS + j0] = pk;
                    }
                }
                __syncthreads();
                #pragma unroll
                for (int ks = 0; ks < 4; ++ks) {
                    const unsigned short* w2p = cW2Tb + lay * CC * CH
                                              + (w * 32 + lr) * CH + jc * 128 + ks * 32 + kg * 8;
                    bf16x8 b0 = *(const bf16x8*)w2p;
                    bf16x8 b1 = *(const bf16x8*)(w2p + 16 * CH);
                    #pragma unroll
                    for (int mt = 0; mt < 4; ++mt) {
                        bf16x8 a = *(const bf16x8*)&Gb[(mt * 16 + lr) * PS + ks * 32 + kg * 8];
                        accB[mt][0] = __builtin_amdgcn_mfma_f32_16x16x32_bf16(a, b0, accB[mt][0], 0, 0, 0);
                        accB[mt][1] = __builtin_amdgcn_mfma_f32_16x16x32_bf16(a, b1, accB[mt][1], 0, 0, 0);
                    }
                }
                __syncthreads();
            }
            #pragma unroll
            for (int mt = 0; mt < 4; ++mt)
                #pragma unroll
                for (int nt = 0; nt < 2; ++nt) {
                    float cb = cb2[lay * CC + (nt ? c1 : c0)];
                    #pragma unroll
                    for (int r = 0; r < 4; ++r) zr[mt][nt][r] += accB[mt][nt][r] + cb;
                }
        }
    }

    // ---------- masked mean over K from registers -> zmean[n][c]
    {
        float msum = 0.f, a0v = 0.f, a1v = 0.f;
        #pragma unroll
        for (int mt = 0; mt < 4; ++mt) {
            f32x4 mk4 = *(const f32x4*)&maskArr[mt * 16 + kg * 4];
            #pragma unroll
            for (int r = 0; r < 4; ++r) {
                msum += mk4[r];
                a0v  += zr[mt][0][r] * mk4[r];
                a1v  += zr[mt][1][r] * mk4[r];
            }
        }
        a0v  += __shfl_xor(a0v, 16);  a0v  += __shfl_xor(a0v, 32);
        a1v  += __shfl_xor(a1v, 16);  a1v  += __shfl_xor(a1v, 32);
        msum += __shfl_xor(msum, 16); msum += __shfl_xor(msum, 32);
        if (kg == 0) {
            float inv = fast_rcp(fmaxf(msum, 1.0f));
            zmean[n * CC + c0] = a0v * inv;
            zmean[n * CC + c1] = a1v * inv;
        }
    }
}

// ---- output kernel: ragged segment mean + node_feat[seed] + final GEMM ----
__global__ __launch_bounds__(256)
void gm_out(const float* __restrict__ zmean,
            const float* __restrict__ node_feat,
            const float* __restrict__ out_W,
            const float* __restrict__ out_b,
            const int*   __restrict__ tg_idx,
            const int*   __restrict__ tg_seg,
            const int*   __restrict__ seed_ids,
            float* __restrict__ outp)
{
    __shared__ float redf[8 * 132];
    __shared__ float zmL[CC], znL[CC], oL[2 * CC];
    const int n = blockIdx.x;
    const int t = threadIdx.x;
    const int q = t & 31, g = t >> 5;

    int a = 0, b = TGN;
    while (a < b) { int mm = (a + b) >> 1; if (tg_seg[mm] < n) a = mm + 1; else b = mm; }
    const int lo = a;
    int a2 = lo, b2 = TGN;
    while (a2 < b2) { int mm = (a2 + b2) >> 1; if (tg_seg[mm] < n + 1) a2 = mm + 1; else b2 = mm; }
    const int hi = a2;

    float4 acc = {0.f, 0.f, 0.f, 0.f};
    for (int i = lo + g; i < hi; i += 8) {
        int nid = tg_idx[i];
        const float4* nf = (const float4*)(node_feat + (size_t)nid * CC);
        float4 v = nf[q];
        acc.x += v.x; acc.y += v.y; acc.z += v.z; acc.w += v.w;
    }
    *(float4*)&redf[g * 132 + q * 4] = acc;
    __syncthreads();
    if (t < CC) {
        float s = 0.f;
        #pragma unroll
        for (int gg = 0; gg < 8; ++gg) s += redf[gg * 132 + t];
        float cnt = (float)(hi - lo);
        znL[t] = s / fmaxf(cnt, 1.0f) + node_feat[(size_t)seed_ids[n] * CC + t];
        zmL[t] = zmean[n * CC + t];
    }
    __syncthreads();
    {
        const int c = t & 127, h = t >> 7;
        const float* src = h ? znL : zmL;
        const float* Wp  = out_W + (size_t)h * CC * 128;
        float o = 0.f;
        for (int j = 0; j < CC; ++j) o += src[j] * Wp[j * 128 + c];
        oL[h * 128 + c] = o;
    }
    __syncthreads();
    if (t < CC) outp[n * 128 + t] = oL[t] + oL[CC + t] + out_b[t];
}

extern "C" void kernel_launch(void* const* d_in, const int* in_sizes, int n_in,
                              void* d_out, int out_size, void* d_ws, size_t ws_size,
                              hipStream_t stream)
{
    const float* edge_feat  = (const float*)d_in[0];
    const float* seed_times = (const float*)d_in[1];
    const float* nbr_time   = (const float*)d_in[2];
    const float* node_feat  = (const float*)d_in[3];
    const float* time_w     = (const float*)d_in[4];
    const float* proj_W     = (const float*)d_in[5];
    const float* proj_b     = (const float*)d_in[6];
    const float* ln1_g      = (const float*)d_in[7];
    const float* ln1_b      = (const float*)d_in[8];
    const float* tW1        = (const float*)d_in[9];
    const float* tb1        = (const float*)d_in[10];
    const float* tW2        = (const float*)d_in[11];
    const float* tb2        = (const float*)d_in[12];
    const float* ln2_g      = (const float*)d_in[13];
    const float* ln2_b      = (const float*)d_in[14];
    const float* cW1        = (const float*)d_in[15];
    const float* cb1        = (const float*)d_in[16];
    const float* cW2        = (const float*)d_in[17];
    const float* cb2        = (const float*)d_in[18];
    const float* out_W      = (const float*)d_in[19];
    const float* out_b      = (const float*)d_in[20];
    const int*   nbr_nids   = (const int*)d_in[21];
    const int*   tg_idx     = (const int*)d_in[22];
    const int*   tg_seg     = (const int*)d_in[23];
    const int*   seed_ids   = (const int*)d_in[24];

    char* ws = (char*)d_ws;
    float*          zmean   = (float*)ws;                            // 1,572,864 B
    unsigned short* projWTb = (unsigned short*)(ws + 1572864);       //    65,536 B
    unsigned short* tW1Tb   = (unsigned short*)(ws + 1638400);       //     8,192 B
    unsigned short* tW2Tb   = (unsigned short*)(ws + 1646592);       //     8,192 B
    unsigned short* cW1Tb   = (unsigned short*)(ws + 1654784);       //   262,144 B
    unsigned short* cW2Tb   = (unsigned short*)(ws + 1916928);       //   262,144 B

    gm_trans<<<288, 256, 0, stream>>>(cW1, cW2, proj_W, cW1Tb, cW2Tb, projWTb);
    gm_prep_small<<<32, 256, 0, stream>>>(tW1, tW2, tW1Tb, tW2Tb);
    gm_mixer<<<NS, 256, 0, stream>>>(edge_feat, seed_times, nbr_time, time_w,
                                     proj_b, ln1_g, ln1_b, tb1, tb2, ln2_g, ln2_b,
                                     cb1, cb2, nbr_nids,
                                     projWTb, tW1Tb, tW2Tb, cW1Tb, cW2Tb, zmean);
    gm_out<<<NS, 256, 0, stream>>>(zmean, node_feat, out_W, out_b,
                                   tg_idx, tg_seg, seed_ids, (float*)d_out);
}